// Round 12
// baseline (215.857 us; speedup 1.0000x reference)
//
#include <hip/hip_runtime.h>
#include <hip/hip_bf16.h>
#include <stdint.h>

// ---------- common types / helpers ----------
typedef __attribute__((ext_vector_type(8))) short short8;   // 8 bf16 = 4 VGPR (MFMA A/B frag)
typedef __attribute__((ext_vector_type(4))) float f32x4;    // MFMA C/D frag
typedef __attribute__((ext_vector_type(4))) float f4;
typedef __attribute__((ext_vector_type(4))) short s4;

typedef __attribute__((address_space(1))) const void gvoid_t;
typedef __attribute__((address_space(3))) void lvoid_t;

__device__ __forceinline__ void gload_lds16(const void* g, void* l) {
  __builtin_amdgcn_global_load_lds((gvoid_t*)g, (lvoid_t*)l, 16, 0, 0);
}

__device__ __forceinline__ ushort f2b(float f) {  // f32 -> bf16 RNE
  union { float f; uint32_t u; } v; v.f = f;
  return (ushort)((v.u + 0x7fffu + ((v.u >> 16) & 1u)) >> 16);
}
__device__ __forceinline__ float b2f(ushort b) {
  union { uint32_t u; float f; } v; v.u = ((uint32_t)b) << 16;
  return v.f;
}

template <int N> __device__ __forceinline__ void wait_vmcnt();
template <> __device__ __forceinline__ void wait_vmcnt<0>() { asm volatile("s_waitcnt vmcnt(0)" ::: "memory"); }

__device__ __forceinline__ void wait_lgkm0() {
  asm volatile("s_waitcnt lgkmcnt(0)" ::: "memory");
  __builtin_amdgcn_sched_barrier(0);   // rule #18: keep MFMA below the wait
}
__device__ __forceinline__ void barrier_fence() {
  asm volatile("s_barrier" ::: "memory");
}

// ---------- prep: f32->bf16 casts + rope cos/sin table (one launch) ----------
__global__ void prep_kernel(const float* __restrict__ x, const float* __restrict__ wq,
                            const float* __restrict__ wo,
                            ushort* __restrict__ Xb, ushort* __restrict__ Wq,
                            ushort* __restrict__ Wo, float2* __restrict__ tab) {
  int b = blockIdx.x, tid = threadIdx.x;
  const float* in; ushort* out; int i;
  if (b < 12288)      { in = x;  out = Xb; i = b * 256 + tid; }
  else if (b < 15744) { in = wq; out = Wq; i = (b - 12288) * 256 + tid; }
  else if (b < 18048) { in = wo; out = Wo; i = (b - 15744) * 256 + tid; }
  else {
    int pos = tid >> 4, fi = tid & 15;
    float inv_freq = __expf(-(float)fi * 0.5756462732485115f);  // ln(10000)/16
    float ang = (float)pos * inv_freq;
    float sn, c;
    __sincosf(ang, &sn, &c);
    tab[tid] = make_float2(c, sn);
    return;
  }
  f4 v = ((const f4*)in)[i];
  s4 o;
  o.x = (short)f2b(v.x); o.y = (short)f2b(v.y);
  o.z = (short)f2b(v.z); o.w = (short)f2b(v.w);
  ((s4*)out)[i] = o;
}

// ---------- gemm6 core (unchanged structure; best measured) ----------
// C[M,N] = A[M,K] @ B[N,K]^T, BM=256. 2 ks-phases/K-tile, XOR-folded LDS
// addressing, one vmcnt(0)+barrier per tile, XCD-owned bm chunks.
template <int BN, typename OutT>
__global__ __launch_bounds__(512, 2) void gemm6(const ushort* __restrict__ A,
                                                const ushort* __restrict__ B,
                                                OutT* __restrict__ C,
                                                int N, int K) {
  constexpr int NF = BN / 32;
  constexpr int RB = BN / 2;
  constexpr int ABUF = 256 * 64;
  constexpr int BBUF = BN * 64;
  constexpr uint ABYTE = ABUF * 2;
  constexpr uint BBYTE = BBUF * 2;
  constexpr int BRND = BN / 64;
  constexpr int BTW = (BN % 64) / 8;

  __shared__ ushort As[2 * ABUF];
  __shared__ ushort Bs[2 * BBUF];

  const int tid = threadIdx.x;
  const int l = tid & 63, w = tid >> 6;
  const int wr = w >> 1, wc = w & 1;
  const int r16 = l & 15, kh = l >> 4;
  const int sc = (l & 7) ^ (l >> 3);
  const int srow = w * 8 + (l >> 3);

  const int xcd = blockIdx.x & 7;
  const int ii = blockIdx.x >> 3;
  const int bm = xcd * 4 + (ii & 3);
  const int bn = ii >> 2;
  const ushort* Ag = A + (size_t)bm * 256 * K;
  const ushort* Bg = B + (size_t)bn * BN * K;
  const int NT = K >> 6;

  const char* AsR = (const char*)As;
  const char* BsR = (const char*)Bs;
  const uint khsw = ((uint)kh * 16) ^ ((uint)(r16 & 7) * 16);
  const uint PA = (uint)(wr * 64 + r16) * 128 + khsw;
  const uint PB = (uint)(wc * RB + r16) * 128 + khsw;

  const ushort* ga[4];
  const ushort* gb[BRND];
  const ushort* gbt = nullptr;
#pragma unroll
  for (int i = 0; i < 4; ++i) ga[i] = Ag + (size_t)(i * 64 + srow) * K + sc * 8;
#pragma unroll
  for (int i = 0; i < BRND; ++i) gb[i] = Bg + (size_t)(i * 64 + srow) * K + sc * 8;
  if constexpr (BTW > 0) gbt = Bg + (size_t)(BRND * 64 + srow) * K + sc * 8;

#pragma unroll
  for (int i = 0; i < 4; ++i) gload_lds16(ga[i], As + i * 4096 + w * 512);
#pragma unroll
  for (int i = 0; i < BRND; ++i) gload_lds16(gb[i], Bs + i * 4096 + w * 512);
  if constexpr (BTW > 0) { if (w < BTW) gload_lds16(gbt, Bs + BRND * 4096 + w * 512); }
#pragma unroll
  for (int i = 0; i < 4; ++i) ga[i] += 64;
#pragma unroll
  for (int i = 0; i < BRND; ++i) gb[i] += 64;
  if constexpr (BTW > 0) gbt += 64;
  wait_vmcnt<0>();
  barrier_fence();

  f32x4 acc[4][NF] = {};
  short8 afr[4], bfr[NF];

  for (int u = 0; u < NT; ++u) {
    const int cur = u & 1;
    const uint aoff = cur ? ABYTE : 0u;
    const uint boff = cur ? BBYTE : 0u;
    ushort* An = As + (cur ^ 1) * ABUF;
    ushort* Bn = Bs + (cur ^ 1) * BBUF;
    const bool st = (u + 1 < NT);

    {
      const uint pa = PA + aoff, pb = PB + boff;
#pragma unroll
      for (int m = 0; m < 4; ++m) afr[m] = *(const short8*)(AsR + pa + m * 2048);
#pragma unroll
      for (int n = 0; n < NF; ++n) bfr[n] = *(const short8*)(BsR + pb + n * 2048);
    }
    if (st) {
#pragma unroll
      for (int i = 0; i < 4; ++i) gload_lds16(ga[i], An + i * 4096 + w * 512);
    }
    wait_lgkm0();
    __builtin_amdgcn_s_setprio(1);
#pragma unroll
    for (int m = 0; m < 4; ++m)
#pragma unroll
      for (int n = 0; n < NF; ++n)
        acc[m][n] = __builtin_amdgcn_mfma_f32_16x16x32_bf16(afr[m], bfr[n], acc[m][n], 0, 0, 0);
    __builtin_amdgcn_s_setprio(0);

    {
      const uint pa = (PA ^ 64u) + aoff, pb = (PB ^ 64u) + boff;
#pragma unroll
      for (int m = 0; m < 4; ++m) afr[m] = *(const short8*)(AsR + pa + m * 2048);
#pragma unroll
      for (int n = 0; n < NF; ++n) bfr[n] = *(const short8*)(BsR + pb + n * 2048);
    }
    if (st) {
#pragma unroll
      for (int i = 0; i < BRND; ++i) gload_lds16(gb[i], Bn + i * 4096 + w * 512);
      if constexpr (BTW > 0) { if (w < BTW) gload_lds16(gbt, Bn + BRND * 4096 + w * 512); }
    }
    wait_lgkm0();
    __builtin_amdgcn_s_setprio(1);
#pragma unroll
    for (int m = 0; m < 4; ++m)
#pragma unroll
      for (int n = 0; n < NF; ++n)
        acc[m][n] = __builtin_amdgcn_mfma_f32_16x16x32_bf16(afr[m], bfr[n], acc[m][n], 0, 0, 0);
    __builtin_amdgcn_s_setprio(0);

#pragma unroll
    for (int i = 0; i < 4; ++i) ga[i] += 64;
#pragma unroll
    for (int i = 0; i < BRND; ++i) gb[i] += 64;
    if constexpr (BTW > 0) gbt += 64;
    wait_vmcnt<0>();
    barrier_fence();
  }

  const int rowb = bm * 256 + wr * 64;
  const int colb = bn * BN + wc * RB;
#pragma unroll
  for (int m = 0; m < 4; ++m)
#pragma unroll
    for (int n = 0; n < NF; ++n)
#pragma unroll
      for (int r = 0; r < 4; ++r) {
        int row = rowb + m * 16 + kh * 4 + r;
        int col = colb + n * 16 + r16;
        float val = acc[m][n][r];
        if constexpr (sizeof(OutT) == 2) C[(size_t)row * N + col] = f2b(val);
        else                             C[(size_t)row * N + col] = val;
      }
}

// ---------- gemm6r: gemm6<288> + fused RoPE epilogue ----------
// Writes Qr[32][16][256][96] (roped), Kr[32][4][256][96] (roped),
// Vr[32][4][256][96] (plain). RoPE pair (d, d+16) = (acc[m][n], acc[m][n+-1])
// in-thread, except the straddling segment at the wc boundary (n=8 for wc0 /
// n=0 for wc1) exchanged via LDS. pos: seg0 = bm&15, seg1 = wr*4+m,
// seg2 = kh*4+r; freq index = r16.
__global__ __launch_bounds__(512, 2) void gemm6r(const ushort* __restrict__ A,
                                                 const ushort* __restrict__ B,
                                                 ushort* __restrict__ Qr,
                                                 ushort* __restrict__ Kr,
                                                 ushort* __restrict__ Vr,
                                                 const float2* __restrict__ Tab,
                                                 int K) {
  constexpr int BN = 288;
  constexpr int NF = 9;
  constexpr int RB = 144;
  constexpr int ABUF = 256 * 64;
  constexpr int BBUF = BN * 64;
  constexpr uint ABYTE = ABUF * 2;
  constexpr uint BBYTE = BBUF * 2;
  constexpr int BRND = 4;
  constexpr int BTW = 4;

  __shared__ ushort As[2 * ABUF];
  __shared__ ushort Bs[2 * BBUF];

  const int tid = threadIdx.x;
  const int l = tid & 63, w = tid >> 6;
  const int wr = w >> 1, wc = w & 1;
  const int r16 = l & 15, kh = l >> 4;
  const int sc = (l & 7) ^ (l >> 3);
  const int srow = w * 8 + (l >> 3);

  const int xcd = blockIdx.x & 7;
  const int ii = blockIdx.x >> 3;
  const int bm = xcd * 4 + (ii & 3);
  const int bn = ii >> 2;
  const ushort* Ag = A + (size_t)bm * 256 * K;
  const ushort* Bg = B + (size_t)bn * BN * K;
  const int NT = K >> 6;

  const char* AsR = (const char*)As;
  const char* BsR = (const char*)Bs;
  const uint khsw = ((uint)kh * 16) ^ ((uint)(r16 & 7) * 16);
  const uint PA = (uint)(wr * 64 + r16) * 128 + khsw;
  const uint PB = (uint)(wc * RB + r16) * 128 + khsw;

  const ushort* ga[4];
  const ushort* gb[BRND];
  const ushort* gbt;
#pragma unroll
  for (int i = 0; i < 4; ++i) ga[i] = Ag + (size_t)(i * 64 + srow) * K + sc * 8;
#pragma unroll
  for (int i = 0; i < BRND; ++i) gb[i] = Bg + (size_t)(i * 64 + srow) * K + sc * 8;
  gbt = Bg + (size_t)(BRND * 64 + srow) * K + sc * 8;

#pragma unroll
  for (int i = 0; i < 4; ++i) gload_lds16(ga[i], As + i * 4096 + w * 512);
#pragma unroll
  for (int i = 0; i < BRND; ++i) gload_lds16(gb[i], Bs + i * 4096 + w * 512);
  if (w < BTW) gload_lds16(gbt, Bs + BRND * 4096 + w * 512);
#pragma unroll
  for (int i = 0; i < 4; ++i) ga[i] += 64;
#pragma unroll
  for (int i = 0; i < BRND; ++i) gb[i] += 64;
  gbt += 64;
  wait_vmcnt<0>();
  barrier_fence();

  f32x4 acc[4][NF] = {};
  short8 afr[4], bfr[NF];

  for (int u = 0; u < NT; ++u) {
    const int cur = u & 1;
    const uint aoff = cur ? ABYTE : 0u;
    const uint boff = cur ? BBYTE : 0u;
    ushort* An = As + (cur ^ 1) * ABUF;
    ushort* Bn = Bs + (cur ^ 1) * BBUF;
    const bool st = (u + 1 < NT);

    {
      const uint pa = PA + aoff, pb = PB + boff;
#pragma unroll
      for (int m = 0; m < 4; ++m) afr[m] = *(const short8*)(AsR + pa + m * 2048);
#pragma unroll
      for (int n = 0; n < NF; ++n) bfr[n] = *(const short8*)(BsR + pb + n * 2048);
    }
    if (st) {
#pragma unroll
      for (int i = 0; i < 4; ++i) gload_lds16(ga[i], An + i * 4096 + w * 512);
    }
    wait_lgkm0();
    __builtin_amdgcn_s_setprio(1);
#pragma unroll
    for (int m = 0; m < 4; ++m)
#pragma unroll
      for (int n = 0; n < NF; ++n)
        acc[m][n] = __builtin_amdgcn_mfma_f32_16x16x32_bf16(afr[m], bfr[n], acc[m][n], 0, 0, 0);
    __builtin_amdgcn_s_setprio(0);

    {
      const uint pa = (PA ^ 64u) + aoff, pb = (PB ^ 64u) + boff;
#pragma unroll
      for (int m = 0; m < 4; ++m) afr[m] = *(const short8*)(AsR + pa + m * 2048);
#pragma unroll
      for (int n = 0; n < NF; ++n) bfr[n] = *(const short8*)(BsR + pb + n * 2048);
    }
    if (st) {
#pragma unroll
      for (int i = 0; i < BRND; ++i) gload_lds16(gb[i], Bn + i * 4096 + w * 512);
      if (w < BTW) gload_lds16(gbt, Bn + BRND * 4096 + w * 512);
    }
    wait_lgkm0();
    __builtin_amdgcn_s_setprio(1);
#pragma unroll
    for (int m = 0; m < 4; ++m)
#pragma unroll
      for (int n = 0; n < NF; ++n)
        acc[m][n] = __builtin_amdgcn_mfma_f32_16x16x32_bf16(afr[m], bfr[n], acc[m][n], 0, 0, 0);
    __builtin_amdgcn_s_setprio(0);

#pragma unroll
    for (int i = 0; i < 4; ++i) ga[i] += 64;
#pragma unroll
    for (int i = 0; i < BRND; ++i) gb[i] += 64;
    gbt += 64;
    wait_vmcnt<0>();
    barrier_fence();
  }

  // ===== fused RoPE epilogue =====
  // 1) exchange straddle frag via LDS (alias As): Xc[w][m][kh*4+r][r16]
  float* Xc = (float*)As;
  const int myN = wc ? 0 : 8;
#pragma unroll
  for (int m = 0; m < 4; ++m)
#pragma unroll
    for (int r = 0; r < 4; ++r)
      Xc[(((w * 4 + m) * 16) + kh * 4 + r) * 16 + r16] = acc[m][myN][r];
  __syncthreads();
  float xp[4][4];
#pragma unroll
  for (int m = 0; m < 4; ++m)
#pragma unroll
    for (int r = 0; r < 4; ++r)
      xp[m][r] = Xc[((((w ^ 1) * 4 + m) * 16) + kh * 4 + r) * 16 + r16];

  // 2) per-frag rope + write
  float c0, s0;
  { float2 t = Tab[(bm & 15) * 16 + r16]; c0 = t.x; s0 = t.y; }
  float c1[4], s1[4], c2[4], s2[4];
#pragma unroll
  for (int m = 0; m < 4; ++m) { float2 t = Tab[(wr * 4 + m) * 16 + r16]; c1[m] = t.x; s1[m] = t.y; }
#pragma unroll
  for (int r = 0; r < 4; ++r) { float2 t = Tab[(kh * 4 + r) * 16 + r16]; c2[r] = t.x; s2[r] = t.y; }

#pragma unroll
  for (int n = 0; n < NF; ++n) {
    const int colb_n = bn * 288 + wc * 144 + n * 16;
    const int q6 = (3 * wc + n) % 6;
    const int seg = q6 >> 1, hi = q6 & 1;
    const int head = 3 * bn + wc + (3 * wc + n) / 6;     // col_base / 96
    const bool isV = colb_n >= 1920;
    const bool isK = (colb_n >= 1536) && !isV;
    ushort* dst;
    if (isV)       dst = Vr + ((size_t)(bm * 4 + (head - 20)) * 256) * 96 + 16 * q6 + r16;
    else if (isK)  dst = Kr + ((size_t)(bm * 4 + (head - 16)) * 256) * 96 + 16 * q6 + r16;
    else           dst = Qr + ((size_t)(bm * 16 + head) * 256) * 96 + 16 * q6 + r16;
#pragma unroll
    for (int m = 0; m < 4; ++m)
#pragma unroll
      for (int r = 0; r < 4; ++r) {
        const int s = wr * 64 + m * 16 + kh * 4 + r;
        const float val = acc[m][n][r];
        float outv;
        if (isV) {
          outv = val;
        } else {
          float c, sn;
          if (seg == 0)      { c = c0;    sn = s0;    }
          else if (seg == 1) { c = c1[m]; sn = s1[m]; }
          else               { c = c2[r]; sn = s2[r]; }
          const float part = (n == myN) ? xp[m][r] : acc[m][n + (hi ? -1 : 1)][r];
          outv = hi ? (part * sn + val * c) : (val * c - part * sn);
        }
        dst[(size_t)s * 96] = f2b(outv);
      }
  }
}

// ---------- V transpose: Vr [slice][256][96] -> Vt [slice][96][256] ----------
__global__ void vtrans_kernel(const ushort* __restrict__ Vr, ushort* __restrict__ Vt) {
  int tau = blockIdx.x * 256 + threadIdx.x;   // 49152 tiles
  int slice = tau / 384;
  int rem = tau - slice * 384;
  int dt = rem >> 5;        // 0..11
  int st = rem & 31;        // 0..31
  const ushort* src = Vr + (size_t)slice * 24576 + (size_t)(st * 8) * 96 + dt * 8;
  ushort* dst = Vt + (size_t)slice * 24576 + (size_t)(dt * 8) * 256 + st * 8;
  short8 rr[8];
#pragma unroll
  for (int j = 0; j < 8; ++j) rr[j] = *(const short8*)(src + (size_t)j * 96);
#pragma unroll
  for (int jj = 0; jj < 8; ++jj) {
    short8 oo;
#pragma unroll
    for (int j = 0; j < 8; ++j) oo[j] = rr[j][jj];
    *(short8*)(dst + (size_t)jj * 256) = oo;
  }
}

// ---------- attention: one block per (bt, g, qhalf); K/V staged once in LDS ----------
__global__ __launch_bounds__(512, 2) void attn2_kernel(
    const ushort* __restrict__ Q,   // [32][16][256][96]
    const ushort* __restrict__ Kr,  // [32][4][256][96]
    const ushort* __restrict__ Vt,  // [32][4][96][256]
    const int* __restrict__ mask,   // [32][256]
    ushort* __restrict__ Out) {     // [8192][1536] bf16
  __shared__ ushort Ks[256 * 104];
  __shared__ ushort Vs[96 * 264];
  __shared__ ushort Ps[8][16 * 136];
  __shared__ float Mb[256];

  const int b = blockIdx.x;
  const int qt = b & 1;
  const int g = (b >> 1) & 3;
  const int bt = b >> 3;
  const int t = threadIdx.x;
  const int l = t & 63, w = t >> 6;
  const int r16 = l & 15, kh = l >> 4;
  const int h = g * 4 + (w >> 1);
  const int qc = w & 1;

  const ushort* Kp = Kr + (size_t)(bt * 4 + g) * 256 * 96;
  const ushort* Vp = Vt + (size_t)(bt * 4 + g) * 96 * 256;

  {
    int r = t >> 1, ch = t & 1;
#pragma unroll
    for (int j = 0; j < 6; ++j)
      *(short8*)(&Ks[r * 104 + ch * 48 + j * 8]) =
          *(const short8*)(Kp + (size_t)r * 96 + ch * 48 + j * 8);
  }
#pragma unroll
  for (int i = 0; i < 6; ++i) {
    int c = t + i * 512;
    int vr = c >> 5, vc = c & 31;
    *(short8*)(&Vs[vr * 264 + vc * 8]) =
        *(const short8*)(Vp + (size_t)vr * 256 + vc * 8);
  }
  if (t < 256) Mb[t] = mask[bt * 256 + t] ? 0.0f : -1.0e9f;
  __syncthreads();

  const ushort* Qp = Q + ((size_t)(bt * 16 + h) * 256 + qt * 128 + qc * 64) * 96;
  ushort* Pw = &Ps[w][0];
  const float scale = 0.10206207261596575f;  // 1/sqrt(96)

#pragma unroll
  for (int mp = 0; mp < 2; ++mp) {
    const int qb = mp * 32;

    short8 qfA[3], qfB[3];
#pragma unroll
    for (int kc = 0; kc < 3; ++kc) {
      qfA[kc] = *(const short8*)(Qp + (size_t)(qb + r16) * 96 + kc * 32 + kh * 8);
      qfB[kc] = *(const short8*)(Qp + (size_t)(qb + 16 + r16) * 96 + kc * 32 + kh * 8);
    }

    f32x4 scA[16] = {}, scB[16] = {};
#pragma unroll
    for (int f = 0; f < 16; ++f) {
#pragma unroll
      for (int kc = 0; kc < 3; ++kc) {
        short8 kf = *(const short8*)(&Ks[(f * 16 + r16) * 104 + kc * 32 + kh * 8]);
        scA[f] = __builtin_amdgcn_mfma_f32_16x16x32_bf16(qfA[kc], kf, scA[f], 0, 0, 0);
        scB[f] = __builtin_amdgcn_mfma_f32_16x16x32_bf16(qfB[kc], kf, scB[f], 0, 0, 0);
      }
    }

#pragma unroll
    for (int f = 0; f < 16; ++f) {
      float mb = Mb[f * 16 + r16];
#pragma unroll
      for (int r = 0; r < 4; ++r) {
        scA[f][r] = scA[f][r] * scale + mb;
        scB[f][r] = scB[f][r] * scale + mb;
      }
    }

    float invA[4], invB[4];
#pragma unroll
    for (int reg = 0; reg < 4; ++reg) {
      float mxA = -3.0e38f, mxB = -3.0e38f;
#pragma unroll
      for (int f = 0; f < 16; ++f) { mxA = fmaxf(mxA, scA[f][reg]); mxB = fmaxf(mxB, scB[f][reg]); }
      for (int o = 8; o >= 1; o >>= 1) { mxA = fmaxf(mxA, __shfl_xor(mxA, o, 64)); mxB = fmaxf(mxB, __shfl_xor(mxB, o, 64)); }
      float smA = 0.f, smB = 0.f;
#pragma unroll
      for (int f = 0; f < 16; ++f) {
        float pA = __expf(scA[f][reg] - mxA);
        float pB = __expf(scB[f][reg] - mxB);
        scA[f][reg] = pA; scB[f][reg] = pB;
        smA += pA; smB += pB;
      }
      for (int o = 8; o >= 1; o >>= 1) { smA += __shfl_xor(smA, o, 64); smB += __shfl_xor(smB, o, 64); }
      invA[reg] = 1.0f / smA;
      invB[reg] = 1.0f / smB;
    }

    short8 pfA[8], pfB[8];
#pragma unroll
    for (int ck = 0; ck < 2; ++ck) {
#pragma unroll
      for (int f = 0; f < 8; ++f)
#pragma unroll
        for (int reg = 0; reg < 4; ++reg)
          Pw[(kh * 4 + reg) * 136 + f * 16 + r16] = f2b(scA[ck * 8 + f][reg]);
#pragma unroll
      for (int kc = 0; kc < 4; ++kc)
        pfA[ck * 4 + kc] = *(const short8*)(&Pw[r16 * 136 + kc * 32 + kh * 8]);
    }
#pragma unroll
    for (int ck = 0; ck < 2; ++ck) {
#pragma unroll
      for (int f = 0; f < 8; ++f)
#pragma unroll
        for (int reg = 0; reg < 4; ++reg)
          Pw[(kh * 4 + reg) * 136 + f * 16 + r16] = f2b(scB[ck * 8 + f][reg]);
#pragma unroll
      for (int kc = 0; kc < 4; ++kc)
        pfB[ck * 4 + kc] = *(const short8*)(&Pw[r16 * 136 + kc * 32 + kh * 8]);
    }

    f32x4 oA[6] = {}, oB[6] = {};
#pragma unroll
    for (int dt = 0; dt < 6; ++dt) {
#pragma unroll
      for (int kc = 0; kc < 8; ++kc) {
        short8 vf = *(const short8*)(&Vs[(dt * 16 + r16) * 264 + kc * 32 + kh * 8]);
        oA[dt] = __builtin_amdgcn_mfma_f32_16x16x32_bf16(pfA[kc], vf, oA[dt], 0, 0, 0);
        oB[dt] = __builtin_amdgcn_mfma_f32_16x16x32_bf16(pfB[kc], vf, oB[dt], 0, 0, 0);
      }
    }

    const int rbase = bt * 256 + qt * 128 + qc * 64 + qb;
#pragma unroll
    for (int dt = 0; dt < 6; ++dt)
#pragma unroll
      for (int reg = 0; reg < 4; ++reg) {
        int col = h * 96 + dt * 16 + r16;
        Out[(size_t)(rbase + kh * 4 + reg) * 1536 + col]      = f2b(oA[dt][reg] * invA[reg]);
        Out[(size_t)(rbase + 16 + kh * 4 + reg) * 1536 + col] = f2b(oB[dt][reg] * invB[reg]);
      }
  }
}

// ---------- launch ----------
extern "C" void kernel_launch(void* const* d_in, const int* in_sizes, int n_in,
                              void* d_out, int out_size, void* d_ws, size_t ws_size,
                              hipStream_t stream) {
  const float* x     = (const float*)d_in[0];   // [2][16][256][1536]
  const int* pmask   = (const int*)d_in[1];     // [32][256]
  const float* w_qkv = (const float*)d_in[2];   // [2304][1536]
  const float* w_o   = (const float*)d_in[3];   // [1536][1536]
  float* out = (float*)d_out;                   // [8192][1536] f32

  char* ws = (char*)d_ws;
  ushort* Xb  = (ushort*)(ws + 0);          // 8192x1536 bf16
  ushort* Wq  = (ushort*)(ws + 25165824);   // 2304x1536 bf16
  ushort* Wo  = (ushort*)(ws + 32243712);   // 1536x1536 bf16
  ushort* Vr  = (ushort*)(ws + 36962304);   // 32x4x256x96 bf16 (6.3 MB, old QKV slot)
  ushort* Qr  = (ushort*)(ws + 74711040);   // 32x16x256x96
  ushort* Kr  = (ushort*)(ws + 99876864);   // 32x4x256x96
  ushort* Vt  = (ushort*)(ws + 106168320);  // 32x4x96x256
  float2* Tab = (float2*)(ws + 112459776);  // 256 x float2 rope table
  ushort* Attn = Xb;                        // reuse Xb slot after gemm1

  prep_kernel<<<18049, 256, 0, stream>>>(x, w_qkv, w_o, Xb, Wq, Wo, Tab);

  gemm6r<<<256, 512, 0, stream>>>(Xb, Wq, Qr, Kr, Vr, Tab, 1536);

  vtrans_kernel<<<192, 256, 0, stream>>>(Vr, Vt);

  attn2_kernel<<<256, 512, 0, stream>>>(Qr, Kr, Vt, pmask, Attn);

  gemm6<192, float><<<256, 512, 0, stream>>>(Attn, Wo, out, 1536, 1536);
}

// Round 13
// 147.000 us; speedup vs baseline: 1.4684x; 1.4684x over previous
//
#include <hip/hip_runtime.h>
#include <hip/hip_bf16.h>
#include <stdint.h>

// ---------- common types / helpers ----------
typedef __attribute__((ext_vector_type(8))) short short8;   // 8 bf16 = 4 VGPR (MFMA A/B frag)
typedef __attribute__((ext_vector_type(4))) float f32x4;    // MFMA C/D frag
typedef __attribute__((ext_vector_type(4))) float f4;
typedef __attribute__((ext_vector_type(4))) short s4;

typedef __attribute__((address_space(1))) const void gvoid_t;
typedef __attribute__((address_space(3))) void lvoid_t;

__device__ __forceinline__ void gload_lds16(const void* g, void* l) {
  __builtin_amdgcn_global_load_lds((gvoid_t*)g, (lvoid_t*)l, 16, 0, 0);
}

__device__ __forceinline__ ushort f2b(float f) {  // f32 -> bf16 RNE
  union { float f; uint32_t u; } v; v.f = f;
  return (ushort)((v.u + 0x7fffu + ((v.u >> 16) & 1u)) >> 16);
}
__device__ __forceinline__ float b2f(ushort b) {
  union { uint32_t u; float f; } v; v.u = ((uint32_t)b) << 16;
  return v.f;
}

template <int N> __device__ __forceinline__ void wait_vmcnt();
template <> __device__ __forceinline__ void wait_vmcnt<0>() { asm volatile("s_waitcnt vmcnt(0)" ::: "memory"); }

__device__ __forceinline__ void wait_lgkm0() {
  asm volatile("s_waitcnt lgkmcnt(0)" ::: "memory");
  __builtin_amdgcn_sched_barrier(0);   // rule #18: keep MFMA below the wait
}
__device__ __forceinline__ void barrier_fence() {
  asm volatile("s_barrier" ::: "memory");
}

// ---------- prep: f32->bf16 casts + rope cos/sin table (one launch) ----------
__global__ void prep_kernel(const float* __restrict__ x, const float* __restrict__ wq,
                            const float* __restrict__ wo,
                            ushort* __restrict__ Xb, ushort* __restrict__ Wq,
                            ushort* __restrict__ Wo, float2* __restrict__ tab) {
  int b = blockIdx.x, tid = threadIdx.x;
  const float* in; ushort* out; int i;
  if (b < 12288)      { in = x;  out = Xb; i = b * 256 + tid; }
  else if (b < 15744) { in = wq; out = Wq; i = (b - 12288) * 256 + tid; }
  else if (b < 18048) { in = wo; out = Wo; i = (b - 15744) * 256 + tid; }
  else {
    int pos = tid >> 4, fi = tid & 15;
    float inv_freq = __expf(-(float)fi * 0.5756462732485115f);  // ln(10000)/16
    float ang = (float)pos * inv_freq;
    float sn, c;
    __sincosf(ang, &sn, &c);
    tab[tid] = make_float2(c, sn);
    return;
  }
  f4 v = ((const f4*)in)[i];
  s4 o;
  o.x = (short)f2b(v.x); o.y = (short)f2b(v.y);
  o.z = (short)f2b(v.z); o.w = (short)f2b(v.w);
  ((s4*)out)[i] = o;
}

// ---------- gemm6 (round-7 structure, best measured: 57.1us each) ----------
// C[M,N] = A[M,K] @ B[N,K]^T, BM=256. 2 ks-phases/K-tile, XOR-folded LDS
// addressing, one vmcnt(0)+barrier per tile, XCD-owned bm chunks.
template <int BN, typename OutT>
__global__ __launch_bounds__(512, 2) void gemm6(const ushort* __restrict__ A,
                                                const ushort* __restrict__ B,
                                                OutT* __restrict__ C,
                                                int N, int K) {
  constexpr int NF = BN / 32;
  constexpr int RB = BN / 2;
  constexpr int ABUF = 256 * 64;
  constexpr int BBUF = BN * 64;
  constexpr uint ABYTE = ABUF * 2;
  constexpr uint BBYTE = BBUF * 2;
  constexpr int BRND = BN / 64;
  constexpr int BTW = (BN % 64) / 8;

  __shared__ ushort As[2 * ABUF];
  __shared__ ushort Bs[2 * BBUF];

  const int tid = threadIdx.x;
  const int l = tid & 63, w = tid >> 6;
  const int wr = w >> 1, wc = w & 1;
  const int r16 = l & 15, kh = l >> 4;
  const int sc = (l & 7) ^ (l >> 3);
  const int srow = w * 8 + (l >> 3);

  const int xcd = blockIdx.x & 7;
  const int ii = blockIdx.x >> 3;
  const int bm = xcd * 4 + (ii & 3);
  const int bn = ii >> 2;
  const ushort* Ag = A + (size_t)bm * 256 * K;
  const ushort* Bg = B + (size_t)bn * BN * K;
  const int NT = K >> 6;

  const char* AsR = (const char*)As;
  const char* BsR = (const char*)Bs;
  const uint khsw = ((uint)kh * 16) ^ ((uint)(r16 & 7) * 16);
  const uint PA = (uint)(wr * 64 + r16) * 128 + khsw;
  const uint PB = (uint)(wc * RB + r16) * 128 + khsw;

  const ushort* ga[4];
  const ushort* gb[BRND];
  const ushort* gbt = nullptr;
#pragma unroll
  for (int i = 0; i < 4; ++i) ga[i] = Ag + (size_t)(i * 64 + srow) * K + sc * 8;
#pragma unroll
  for (int i = 0; i < BRND; ++i) gb[i] = Bg + (size_t)(i * 64 + srow) * K + sc * 8;
  if constexpr (BTW > 0) gbt = Bg + (size_t)(BRND * 64 + srow) * K + sc * 8;

#pragma unroll
  for (int i = 0; i < 4; ++i) gload_lds16(ga[i], As + i * 4096 + w * 512);
#pragma unroll
  for (int i = 0; i < BRND; ++i) gload_lds16(gb[i], Bs + i * 4096 + w * 512);
  if constexpr (BTW > 0) { if (w < BTW) gload_lds16(gbt, Bs + BRND * 4096 + w * 512); }
#pragma unroll
  for (int i = 0; i < 4; ++i) ga[i] += 64;
#pragma unroll
  for (int i = 0; i < BRND; ++i) gb[i] += 64;
  if constexpr (BTW > 0) gbt += 64;
  wait_vmcnt<0>();
  barrier_fence();

  f32x4 acc[4][NF] = {};
  short8 afr[4], bfr[NF];

  for (int u = 0; u < NT; ++u) {
    const int cur = u & 1;
    const uint aoff = cur ? ABYTE : 0u;
    const uint boff = cur ? BBYTE : 0u;
    ushort* An = As + (cur ^ 1) * ABUF;
    ushort* Bn = Bs + (cur ^ 1) * BBUF;
    const bool st = (u + 1 < NT);

    {
      const uint pa = PA + aoff, pb = PB + boff;
#pragma unroll
      for (int m = 0; m < 4; ++m) afr[m] = *(const short8*)(AsR + pa + m * 2048);
#pragma unroll
      for (int n = 0; n < NF; ++n) bfr[n] = *(const short8*)(BsR + pb + n * 2048);
    }
    if (st) {
#pragma unroll
      for (int i = 0; i < 4; ++i) gload_lds16(ga[i], An + i * 4096 + w * 512);
    }
    wait_lgkm0();
    __builtin_amdgcn_s_setprio(1);
#pragma unroll
    for (int m = 0; m < 4; ++m)
#pragma unroll
      for (int n = 0; n < NF; ++n)
        acc[m][n] = __builtin_amdgcn_mfma_f32_16x16x32_bf16(afr[m], bfr[n], acc[m][n], 0, 0, 0);
    __builtin_amdgcn_s_setprio(0);

    {
      const uint pa = (PA ^ 64u) + aoff, pb = (PB ^ 64u) + boff;
#pragma unroll
      for (int m = 0; m < 4; ++m) afr[m] = *(const short8*)(AsR + pa + m * 2048);
#pragma unroll
      for (int n = 0; n < NF; ++n) bfr[n] = *(const short8*)(BsR + pb + n * 2048);
    }
    if (st) {
#pragma unroll
      for (int i = 0; i < BRND; ++i) gload_lds16(gb[i], Bn + i * 4096 + w * 512);
      if constexpr (BTW > 0) { if (w < BTW) gload_lds16(gbt, Bn + BRND * 4096 + w * 512); }
    }
    wait_lgkm0();
    __builtin_amdgcn_s_setprio(1);
#pragma unroll
    for (int m = 0; m < 4; ++m)
#pragma unroll
      for (int n = 0; n < NF; ++n)
        acc[m][n] = __builtin_amdgcn_mfma_f32_16x16x32_bf16(afr[m], bfr[n], acc[m][n], 0, 0, 0);
    __builtin_amdgcn_s_setprio(0);

#pragma unroll
    for (int i = 0; i < 4; ++i) ga[i] += 64;
#pragma unroll
    for (int i = 0; i < BRND; ++i) gb[i] += 64;
    if constexpr (BTW > 0) gbt += 64;
    wait_vmcnt<0>();
    barrier_fence();
  }

  const int rowb = bm * 256 + wr * 64;
  const int colb = bn * BN + wc * RB;
#pragma unroll
  for (int m = 0; m < 4; ++m)
#pragma unroll
    for (int n = 0; n < NF; ++n)
#pragma unroll
      for (int r = 0; r < 4; ++r) {
        int row = rowb + m * 16 + kh * 4 + r;
        int col = colb + n * 16 + r16;
        float val = acc[m][n][r];
        if constexpr (sizeof(OutT) == 2) C[(size_t)row * N + col] = f2b(val);
        else                             C[(size_t)row * N + col] = val;
      }
}

// ---------- in-register Q-rope helper: pair partner is lane^32 (kh^2) ----------
__device__ __forceinline__ short8 shfl_xor32(short8 v) {
  union { short8 s; int i[4]; } a, b;
  a.s = v;
#pragma unroll
  for (int q = 0; q < 4; ++q) b.i[q] = __shfl_xor(a.i[q], 32, 64);
  return b.s;
}
// element j of frag (kc,kh): d = kc*32+kh*8+j, i16 = (kh&1)*8+j.
// kh<2 -> x1 side: out = own*c - partner*sn ; kh>=2 -> out = own*c + partner*sn.
__device__ __forceinline__ short8 rope_frag(short8 v, int pos, int kh, const float2* Tb) {
  short8 p = shfl_xor32(v);
  const float sgn = (kh < 2) ? -1.0f : 1.0f;
  const int ib = pos * 16 + (kh & 1) * 8;
  short8 o;
#pragma unroll
  for (int j = 0; j < 8; ++j) {
    float2 cs = Tb[ib + j];
    o[j] = (short)f2b(b2f((ushort)v[j]) * cs.x + sgn * b2f((ushort)p[j]) * cs.y);
  }
  return o;
}

// ---------- attn3: attention + fused RoPE(Q,K) + fused V-transpose ----------
// One block per (bt, g, qhalf) = 256 blocks x 512 threads. Reads QKV directly
// (gemm1's natural [8192][2304] layout) - no rope kernel, no intermediates.
__global__ __launch_bounds__(512, 1) void attn3_kernel(
    const ushort* __restrict__ QKV,  // [8192][2304] bf16
    const int* __restrict__ mask,    // [32][256]
    const float2* __restrict__ Tab,  // [16][16] float2 (cos,sin)
    ushort* __restrict__ Out) {      // [8192][1536] bf16
  __shared__ ushort Ks[256 * 104];   // roped K, padded stride 104
  __shared__ ushort Vs[96 * 264];    // V^T, padded stride 264
  __shared__ ushort Ps[8][16 * 136];
  __shared__ float Mb[256];
  __shared__ float2 Tb[256];

  const int b = blockIdx.x;
  const int qt = b & 1;
  const int g = (b >> 1) & 3;
  const int bt = b >> 3;
  const int t = threadIdx.x;
  const int l = t & 63, w = t >> 6;
  const int r16 = l & 15, kh = l >> 4;
  const int h = g * 4 + (w >> 1);
  const int qc = w & 1;
  const int t0 = bt & 15;            // seg0 position (temporal)

  if (t < 256) { Tb[t] = Tab[t]; Mb[t] = mask[bt * 256 + t] ? 0.0f : -1.0e9f; }
  __syncthreads();

  // ---- stage K with rope: row r = t>>1; ch0 handles segs 0,1; ch1 seg 2
  {
    const int r = t >> 1, ch = t & 1;
    const ushort* src = QKV + (size_t)(bt * 256 + r) * 2304 + 1536 + g * 96;
    const int p1 = r >> 4, p2 = r & 15;
    if (ch == 0) {
      // seg0 (pos t0): d 0..31
      short8 v0 = *(const short8*)(src + 0);
      short8 v1 = *(const short8*)(src + 8);
      short8 v2 = *(const short8*)(src + 16);
      short8 v3 = *(const short8*)(src + 24);
      short8 o0, o1, o2, o3;
#pragma unroll
      for (int j = 0; j < 8; ++j) {
        float2 ca = Tb[t0 * 16 + j], cb = Tb[t0 * 16 + 8 + j];
        float x1a = b2f((ushort)v0[j]), x2a = b2f((ushort)v2[j]);
        float x1b = b2f((ushort)v1[j]), x2b = b2f((ushort)v3[j]);
        o0[j] = (short)f2b(x1a * ca.x - x2a * ca.y);
        o1[j] = (short)f2b(x1b * cb.x - x2b * cb.y);
        o2[j] = (short)f2b(x1a * ca.y + x2a * ca.x);
        o3[j] = (short)f2b(x1b * cb.y + x2b * cb.x);
      }
      *(short8*)(&Ks[r * 104 + 0])  = o0;
      *(short8*)(&Ks[r * 104 + 8])  = o1;
      *(short8*)(&Ks[r * 104 + 16]) = o2;
      *(short8*)(&Ks[r * 104 + 24]) = o3;
      // seg1 (pos p1): d 32..63
      v0 = *(const short8*)(src + 32);
      v1 = *(const short8*)(src + 40);
      v2 = *(const short8*)(src + 48);
      v3 = *(const short8*)(src + 56);
#pragma unroll
      for (int j = 0; j < 8; ++j) {
        float2 ca = Tb[p1 * 16 + j], cb = Tb[p1 * 16 + 8 + j];
        float x1a = b2f((ushort)v0[j]), x2a = b2f((ushort)v2[j]);
        float x1b = b2f((ushort)v1[j]), x2b = b2f((ushort)v3[j]);
        o0[j] = (short)f2b(x1a * ca.x - x2a * ca.y);
        o1[j] = (short)f2b(x1b * cb.x - x2b * cb.y);
        o2[j] = (short)f2b(x1a * ca.y + x2a * ca.x);
        o3[j] = (short)f2b(x1b * cb.y + x2b * cb.x);
      }
      *(short8*)(&Ks[r * 104 + 32]) = o0;
      *(short8*)(&Ks[r * 104 + 40]) = o1;
      *(short8*)(&Ks[r * 104 + 48]) = o2;
      *(short8*)(&Ks[r * 104 + 56]) = o3;
    } else {
      // seg2 (pos p2): d 64..95
      short8 v0 = *(const short8*)(src + 64);
      short8 v1 = *(const short8*)(src + 72);
      short8 v2 = *(const short8*)(src + 80);
      short8 v3 = *(const short8*)(src + 88);
      short8 o0, o1, o2, o3;
#pragma unroll
      for (int j = 0; j < 8; ++j) {
        float2 ca = Tb[p2 * 16 + j], cb = Tb[p2 * 16 + 8 + j];
        float x1a = b2f((ushort)v0[j]), x2a = b2f((ushort)v2[j]);
        float x1b = b2f((ushort)v1[j]), x2b = b2f((ushort)v3[j]);
        o0[j] = (short)f2b(x1a * ca.x - x2a * ca.y);
        o1[j] = (short)f2b(x1b * cb.x - x2b * cb.y);
        o2[j] = (short)f2b(x1a * ca.y + x2a * ca.x);
        o3[j] = (short)f2b(x1b * cb.y + x2b * cb.x);
      }
      *(short8*)(&Ks[r * 104 + 64]) = o0;
      *(short8*)(&Ks[r * 104 + 72]) = o1;
      *(short8*)(&Ks[r * 104 + 80]) = o2;
      *(short8*)(&Ks[r * 104 + 88]) = o3;
    }
  }

  // ---- stage V transposed: Vs[d][s] (coalesced reads, scalar LDS writes)
#pragma unroll
  for (int i = 0; i < 6; ++i) {
    int c = t + i * 512;               // 0..3071 = 256 rows x 12 chunks
    int s = c / 12, dq = c - s * 12;
    short8 vv = *(const short8*)(QKV + (size_t)(bt * 256 + s) * 2304 + 1920 + g * 96 + dq * 8);
#pragma unroll
    for (int j = 0; j < 8; ++j)
      Vs[(dq * 8 + j) * 264 + s] = (ushort)vv[j];
  }
  __syncthreads();

  const ushort* Qp = QKV + (size_t)(bt * 256 + qt * 128 + qc * 64) * 2304 + h * 96;
  ushort* Pw = &Ps[w][0];
  const float scale = 0.10206207261596575f;  // 1/sqrt(96)

#pragma unroll
  for (int mp = 0; mp < 2; ++mp) {
    const int qb = mp * 32;
    const int p1A = qt * 8 + qc * 4 + mp * 2;   // seg1 pos for A rows (uniform)
    const int p1B = p1A + 1;                    // seg1 pos for B rows (+16)

    short8 qfA[3], qfB[3];
    {
      short8 rA0 = *(const short8*)(Qp + (size_t)(qb + r16) * 2304 + 0 + kh * 8);
      short8 rA1 = *(const short8*)(Qp + (size_t)(qb + r16) * 2304 + 32 + kh * 8);
      short8 rA2 = *(const short8*)(Qp + (size_t)(qb + r16) * 2304 + 64 + kh * 8);
      short8 rB0 = *(const short8*)(Qp + (size_t)(qb + 16 + r16) * 2304 + 0 + kh * 8);
      short8 rB1 = *(const short8*)(Qp + (size_t)(qb + 16 + r16) * 2304 + 32 + kh * 8);
      short8 rB2 = *(const short8*)(Qp + (size_t)(qb + 16 + r16) * 2304 + 64 + kh * 8);
      qfA[0] = rope_frag(rA0, t0, kh, Tb);
      qfA[1] = rope_frag(rA1, p1A, kh, Tb);
      qfA[2] = rope_frag(rA2, r16, kh, Tb);   // seg2 pos = s&15 = r16
      qfB[0] = rope_frag(rB0, t0, kh, Tb);
      qfB[1] = rope_frag(rB1, p1B, kh, Tb);
      qfB[2] = rope_frag(rB2, r16, kh, Tb);
    }

    f32x4 scA[16] = {}, scB[16] = {};
#pragma unroll
    for (int f = 0; f < 16; ++f) {
#pragma unroll
      for (int kc = 0; kc < 3; ++kc) {
        short8 kf = *(const short8*)(&Ks[(f * 16 + r16) * 104 + kc * 32 + kh * 8]);
        scA[f] = __builtin_amdgcn_mfma_f32_16x16x32_bf16(qfA[kc], kf, scA[f], 0, 0, 0);
        scB[f] = __builtin_amdgcn_mfma_f32_16x16x32_bf16(qfB[kc], kf, scB[f], 0, 0, 0);
      }
    }

#pragma unroll
    for (int f = 0; f < 16; ++f) {
      float mb = Mb[f * 16 + r16];
#pragma unroll
      for (int r = 0; r < 4; ++r) {
        scA[f][r] = scA[f][r] * scale + mb;
        scB[f][r] = scB[f][r] * scale + mb;
      }
    }

    float invA[4], invB[4];
#pragma unroll
    for (int reg = 0; reg < 4; ++reg) {
      float mxA = -3.0e38f, mxB = -3.0e38f;
#pragma unroll
      for (int f = 0; f < 16; ++f) { mxA = fmaxf(mxA, scA[f][reg]); mxB = fmaxf(mxB, scB[f][reg]); }
      for (int o = 8; o >= 1; o >>= 1) { mxA = fmaxf(mxA, __shfl_xor(mxA, o, 64)); mxB = fmaxf(mxB, __shfl_xor(mxB, o, 64)); }
      float smA = 0.f, smB = 0.f;
#pragma unroll
      for (int f = 0; f < 16; ++f) {
        float pA = __expf(scA[f][reg] - mxA);
        float pB = __expf(scB[f][reg] - mxB);
        scA[f][reg] = pA; scB[f][reg] = pB;
        smA += pA; smB += pB;
      }
      for (int o = 8; o >= 1; o >>= 1) { smA += __shfl_xor(smA, o, 64); smB += __shfl_xor(smB, o, 64); }
      invA[reg] = 1.0f / smA;
      invB[reg] = 1.0f / smB;
    }

    short8 pfA[8], pfB[8];
#pragma unroll
    for (int ck = 0; ck < 2; ++ck) {
#pragma unroll
      for (int f = 0; f < 8; ++f)
#pragma unroll
        for (int reg = 0; reg < 4; ++reg)
          Pw[(kh * 4 + reg) * 136 + f * 16 + r16] = f2b(scA[ck * 8 + f][reg]);
#pragma unroll
      for (int kc = 0; kc < 4; ++kc)
        pfA[ck * 4 + kc] = *(const short8*)(&Pw[r16 * 136 + kc * 32 + kh * 8]);
    }
#pragma unroll
    for (int ck = 0; ck < 2; ++ck) {
#pragma unroll
      for (int f = 0; f < 8; ++f)
#pragma unroll
        for (int reg = 0; reg < 4; ++reg)
          Pw[(kh * 4 + reg) * 136 + f * 16 + r16] = f2b(scB[ck * 8 + f][reg]);
#pragma unroll
      for (int kc = 0; kc < 4; ++kc)
        pfB[ck * 4 + kc] = *(const short8*)(&Pw[r16 * 136 + kc * 32 + kh * 8]);
    }

    f32x4 oA[6] = {}, oB[6] = {};
#pragma unroll
    for (int dt = 0; dt < 6; ++dt) {
#pragma unroll
      for (int kc = 0; kc < 8; ++kc) {
        short8 vf = *(const short8*)(&Vs[(dt * 16 + r16) * 264 + kc * 32 + kh * 8]);
        oA[dt] = __builtin_amdgcn_mfma_f32_16x16x32_bf16(pfA[kc], vf, oA[dt], 0, 0, 0);
        oB[dt] = __builtin_amdgcn_mfma_f32_16x16x32_bf16(pfB[kc], vf, oB[dt], 0, 0, 0);
      }
    }

    const int rbase = bt * 256 + qt * 128 + qc * 64 + qb;
#pragma unroll
    for (int dt = 0; dt < 6; ++dt)
#pragma unroll
      for (int reg = 0; reg < 4; ++reg) {
        int col = h * 96 + dt * 16 + r16;
        Out[(size_t)(rbase + kh * 4 + reg) * 1536 + col]      = f2b(oA[dt][reg] * invA[reg]);
        Out[(size_t)(rbase + 16 + kh * 4 + reg) * 1536 + col] = f2b(oB[dt][reg] * invB[reg]);
      }
  }
}

// ---------- launch ----------
extern "C" void kernel_launch(void* const* d_in, const int* in_sizes, int n_in,
                              void* d_out, int out_size, void* d_ws, size_t ws_size,
                              hipStream_t stream) {
  const float* x     = (const float*)d_in[0];   // [2][16][256][1536]
  const int* pmask   = (const int*)d_in[1];     // [32][256]
  const float* w_qkv = (const float*)d_in[2];   // [2304][1536]
  const float* w_o   = (const float*)d_in[3];   // [1536][1536]
  float* out = (float*)d_out;                   // [8192][1536] f32

  char* ws = (char*)d_ws;
  ushort* Xb  = (ushort*)(ws + 0);          // 8192x1536 bf16
  ushort* Wq  = (ushort*)(ws + 25165824);   // 2304x1536 bf16
  ushort* Wo  = (ushort*)(ws + 32243712);   // 1536x1536 bf16
  ushort* QKV = (ushort*)(ws + 36962304);   // 8192x2304 bf16
  float2* Tab = (float2*)(ws + 74711040);   // 256 x float2 rope table
  ushort* Attn = Xb;                        // reuse Xb slot after gemm1

  prep_kernel<<<18049, 256, 0, stream>>>(x, w_qkv, w_o, Xb, Wq, Wo, Tab);

  gemm6<288, ushort><<<256, 512, 0, stream>>>(Xb, Wq, QKV, 2304, 1536);

  attn3_kernel<<<256, 512, 0, stream>>>(QKV, pmask, Tab, Attn);

  gemm6<192, float><<<256, 512, 0, stream>>>(Attn, Wo, out, 1536, 1536);
}